// Round 5
// baseline (925.748 us; speedup 1.0000x reference)
//
#include <hip/hip_runtime.h>
#include <hip/hip_bf16.h>

// out[b,k,o,f] = entmax15( x[b,f,:] @ W2'[k,:,o] ) * values[k,o,f]
// W2'[k,x,o] = 0.0625 * sum_y bw[k,x,y] * q[k,o,y]   (scale * (alpha-1) folded in)
// b=2048, k=8, o=64, f=128, x=128, y=64
//
// Round-5 structure: block = one b (grid 2048, 4 waves = 4 o-quarters).
// x[b] staged fp16 in LDS ONCE (1 barrier), then each wave loops k=0..7:
// prefetch next-k B-frags (global, consumed one full entmax later -> latency
// hidden), 32 ds_read_b128 A-frags + 32 MFMA, in-register entmax, store.
// Amortizes the A operand 8x (round-4 paid ~36 high-latency global loads PER
// (b,k) pair with ~2-3 in flight = ~40k stall cycles/wave). xh kernel dropped.

using half8_t  = __attribute__((ext_vector_type(8))) _Float16;
using half4_t  = __attribute__((ext_vector_type(4))) _Float16;
using fp16x2   = __attribute__((ext_vector_type(2))) __fp16;   // builtin-compatible
using floatx4  = __attribute__((ext_vector_type(4))) float;

#define NBIS 8    // fp16 bisection iters -> bracket width 0.91*2^-8*2 = 7.1e-3

#if defined(__has_builtin)
#if __has_builtin(__builtin_amdgcn_fdot2)
#define HAS_FDOT2 1
#endif
#endif
#ifndef HAS_FDOT2
#define HAS_FDOT2 0
#endif

__device__ __forceinline__ float frcp(float x) {
#if __has_builtin(__builtin_amdgcn_rcpf)
    return __builtin_amdgcn_rcpf(x);   // 1-ulp rcp; plenty for Newton step sizing
#else
    return 1.0f / x;
#endif
}

// ---------------- Kernel A: W2'[k][o][x] fp16 into workspace ----------------
__global__ __launch_bounds__(256) void w2_kernel(const float* __restrict__ bw,
                                                 const float* __restrict__ qm,
                                                 _Float16* __restrict__ W2h) {
    const int k  = blockIdx.x >> 3;
    const int og = blockIdx.x & 7;          // o-chunk of 8 rows
    __shared__ float Lbw[128 * 65];         // [x][y] padded (+1) -> conflict-free
    __shared__ float Lq[8 * 64];            // [o][y]
    const int t = threadIdx.x;

    const float* bwk = bw + k * 8192;       // [128][64]
    #pragma unroll
    for (int i2 = 0; i2 < 8; ++i2) {
        int i = t + i2 * 256;               // float4 index, 2048 total
        float4 v = ((const float4*)bwk)[i];
        int xx = (i * 4) >> 6, y = (i * 4) & 63;
        float* dst = &Lbw[xx * 65 + y];
        dst[0] = v.x; dst[1] = v.y; dst[2] = v.z; dst[3] = v.w;
    }
    const float* qk = qm + k * 4096 + og * 8 * 64;
    if (t < 128) ((float4*)Lq)[t] = ((const float4*)qk)[t];
    __syncthreads();

    #pragma unroll
    for (int i = 0; i < 4; ++i) {
        int ox = i * 256 + t;               // 1024 outputs: [8 o][128 x]
        int o = ox >> 7, x = ox & 127;
        const float* brow = &Lbw[x * 65];
        const float* qrow = &Lq[o * 64];
        float acc = 0.f;
        #pragma unroll
        for (int y = 0; y < 64; ++y) acc = fmaf(brow[y], qrow[y], acc);
        W2h[(k * 64 + og * 8 + o) * 128 + x] = (_Float16)(acc * 0.0625f);
    }
}

// ---------------- Kernel B: fused GEMM + entmax + scale ----------------
// block = one b; 4 waves; wave qtr owns o in [16*qtr, 16*qtr+16); k-loop 0..7
__global__ __launch_bounds__(256, 4) void satt_kernel(
        const float* __restrict__ xg, const _Float16* __restrict__ W2h,
        const float* __restrict__ values, float* __restrict__ out) {
    const int b = blockIdx.x;
    const int t = threadIdx.x;
    const int qtr = t >> 6, l = t & 63;
    const int q = l >> 4, c16 = l & 15;
    const int o = qtr * 16 + c16;           // this lane's output row (all k)

    __shared__ _Float16 Ash[128 * 136];     // x[b] [f][x] fp16, padded row 136

    // ---- stage x[b] fp32 -> fp16 LDS once (4096 float4, 16/thread) ----
    const float* xb = xg + (size_t)b * 16384;
    #pragma unroll
    for (int j = 0; j < 16; ++j) {
        int c = t + 256 * j;
        int f = c >> 5, x0 = (c & 31) * 4;
        float4 v = ((const float4*)xb)[c];
        half4_t h;
        h[0] = (_Float16)v.x; h[1] = (_Float16)v.y;
        h[2] = (_Float16)v.z; h[3] = (_Float16)v.w;
        *(half4_t*)(&Ash[f * 136 + x0]) = h;
    }
    __syncthreads();

    // B-fragments for k=0; per-k prefetch of k+1 is consumed one entmax later
    const _Float16* w2o = W2h + (o << 7) + q * 8;   // + k*8192 per k
    half8_t bcur[4], bnxt[4];
    #pragma unroll
    for (int kk = 0; kk < 4; ++kk)
        bcur[kk] = *(const half8_t*)(w2o + kk * 32);

    #pragma unroll 2
    for (int k = 0; k < 8; ++k) {
        // prefetch next k's B-frags (wraps at 7 -> harmless reload of k=0)
        const _Float16* w2n = w2o + (((k + 1) & 7) << 13);
        #pragma unroll
        for (int kk = 0; kk < 4; ++kk)
            bnxt[kk] = *(const half8_t*)(w2n + kk * 32);

        // ---- MFMA: z^T[f,o]; A row = f = mt*16+c16 from LDS, B = W2 row o ----
        floatx4 acc[8];
        #pragma unroll
        for (int mt = 0; mt < 8; ++mt) acc[mt] = (floatx4){0.f, 0.f, 0.f, 0.f};
        #pragma unroll
        for (int kk = 0; kk < 4; ++kk) {
            #pragma unroll
            for (int mt = 0; mt < 8; ++mt) {
                half8_t a = *(const half8_t*)(&Ash[(mt * 16 + c16) * 136 + kk * 32 + q * 8]);
                acc[mt] = __builtin_amdgcn_mfma_f32_16x16x32_f16(a, bcur[kk], acc[mt], 0, 0, 0);
            }
        }

        // ---- Entmax-1.5; lane holds f = mt*16 + q*4 + r of row o ----
        // partners (same c16, q 0..3) are lanes l^16, l^32.
        float zz[32];
        #pragma unroll
        for (int mt = 0; mt < 8; ++mt) {
            zz[4 * mt + 0] = acc[mt][0]; zz[4 * mt + 1] = acc[mt][1];
            zz[4 * mt + 2] = acc[mt][2]; zz[4 * mt + 3] = acc[mt][3];
        }
        float m0 = zz[0], m1 = zz[1], m2 = zz[2], m3 = zz[3];
        #pragma unroll
        for (int j = 4; j < 32; j += 4) {
            m0 = fmaxf(m0, zz[j + 0]); m1 = fmaxf(m1, zz[j + 1]);
            m2 = fmaxf(m2, zz[j + 2]); m3 = fmaxf(m3, zz[j + 3]);
        }
        float m = fmaxf(fmaxf(m0, m1), fmaxf(m2, m3));
        m = fmaxf(m, __shfl_xor(m, 16));
        m = fmaxf(m, __shfl_xor(m, 32));

        float tau = m - 1.0f;
        float dm  = 0.9116116523516816f;    // 1 - (1/128)^0.5

#if HAS_FDOT2
        fp16x2 zh[16];
        #pragma unroll
        for (int j = 0; j < 16; ++j)
            zh[j] = __builtin_amdgcn_cvt_pkrtz(zz[2 * j], zz[2 * j + 1]);
        const fp16x2 hzero = { (__fp16)0.f, (__fp16)0.f };
        const fp16x2 hone  = { (__fp16)1.f, (__fp16)1.f };

        #pragma unroll
        for (int it = 0; it < NBIS; ++it) {
            dm *= 0.5f;
            float tm = tau + dm;
            fp16x2 t2 = __builtin_amdgcn_cvt_pkrtz(tm, tm);
            float sa = 0.f, sb = 0.f;
            #pragma unroll
            for (int j = 0; j < 16; j += 2) {
                fp16x2 d0 = __builtin_elementwise_max(zh[j]     - t2, hzero);
                fp16x2 d1 = __builtin_elementwise_max(zh[j + 1] - t2, hzero);
                sa = __builtin_amdgcn_fdot2(d0, d0, sa, false);
                sb = __builtin_amdgcn_fdot2(d1, d1, sb, false);
            }
            float sm = sa + sb;
            sm += __shfl_xor(sm, 16); sm += __shfl_xor(sm, 32);
            tau = (sm >= 1.0f) ? tm : tau;  // f(m-1) >= 0 -> sign test vs 1
        }
        // 2 fp16 Newton steps (monotone for convex f)
        #pragma unroll
        for (int it = 0; it < 2; ++it) {
            fp16x2 t2 = __builtin_amdgcn_cvt_pkrtz(tau, tau);
            float s2a = 0.f, s2b = 0.f, s1a = 0.f, s1b = 0.f;
            #pragma unroll
            for (int j = 0; j < 16; j += 2) {
                fp16x2 d0 = __builtin_elementwise_max(zh[j]     - t2, hzero);
                fp16x2 d1 = __builtin_elementwise_max(zh[j + 1] - t2, hzero);
                s2a = __builtin_amdgcn_fdot2(d0, d0, s2a, false);
                s2b = __builtin_amdgcn_fdot2(d1, d1, s2b, false);
                s1a = __builtin_amdgcn_fdot2(d0, hone, s1a, false);
                s1b = __builtin_amdgcn_fdot2(d1, hone, s1b, false);
            }
            float s2 = s2a + s2b, s1 = s1a + s1b;
            s2 += __shfl_xor(s2, 16); s2 += __shfl_xor(s2, 32);
            s1 += __shfl_xor(s1, 16); s1 += __shfl_xor(s1, 32);
            tau += (s2 - 1.0f) * frcp(fmaxf(s1 + s1, 1e-6f));
        }
#else
        #pragma unroll
        for (int it = 0; it < NBIS + 4; ++it) {
            dm *= 0.5f;
            float tm = tau + dm;
            float sa = 0.f, sb = 0.f;
            #pragma unroll
            for (int j = 0; j < 32; j += 2) {
                float d0 = fmaxf(zz[j] - tm, 0.f);
                float d1 = fmaxf(zz[j + 1] - tm, 0.f);
                sa = fmaf(d0, d0, sa); sb = fmaf(d1, d1, sb);
            }
            float sm = sa + sb;
            sm += __shfl_xor(sm, 16); sm += __shfl_xor(sm, 32);
            tau = (sm >= 1.0f) ? tm : tau;
        }
        {
            float s2a = 0.f, s2b = 0.f, s1a = 0.f, s1b = 0.f;
            #pragma unroll
            for (int j = 0; j < 32; j += 2) {
                float d0 = fmaxf(zz[j] - tau, 0.f);
                float d1 = fmaxf(zz[j + 1] - tau, 0.f);
                s2a = fmaf(d0, d0, s2a); s2b = fmaf(d1, d1, s2b);
                s1a += d0; s1b += d1;
            }
            float s2 = s2a + s2b, s1 = s1a + s1b;
            s2 += __shfl_xor(s2, 16); s2 += __shfl_xor(s2, 32);
            s1 += __shfl_xor(s1, 16); s1 += __shfl_xor(s1, 32);
            tau += (s2 - 1.0f) * frcp(fmaxf(s1 + s1, 1e-6f));
        }
#endif
        // final fp32 Newton polish (removes fp16 root bias; err -> ~1e-5)
        {
            float s2a = 0.f, s2b = 0.f, s1a = 0.f, s1b = 0.f;
            #pragma unroll
            for (int j = 0; j < 32; j += 2) {
                float d0 = fmaxf(zz[j] - tau, 0.f);
                float d1 = fmaxf(zz[j + 1] - tau, 0.f);
                s2a = fmaf(d0, d0, s2a); s2b = fmaf(d1, d1, s2b);
                s1a += d0; s1b += d1;
            }
            float s2 = s2a + s2b, s1 = s1a + s1b;
            s2 += __shfl_xor(s2, 16); s2 += __shfl_xor(s2, 32);
            s1 += __shfl_xor(s1, 16); s1 += __shfl_xor(s1, 32);
            tau += (s2 - 1.0f) * frcp(fmaxf(s1 + s1, 1e-6f));
        }

        // final p, normalization, scale by values, store
        float ps0 = 0.f, ps1 = 0.f;
        #pragma unroll
        for (int j = 0; j < 32; j += 2) {
            float d0 = fmaxf(zz[j] - tau, 0.f);
            float d1 = fmaxf(zz[j + 1] - tau, 0.f);
            float p0 = d0 * d0, p1 = d1 * d1;
            zz[j] = p0; zz[j + 1] = p1;
            ps0 += p0; ps1 += p1;
        }
        float ps = ps0 + ps1;
        ps += __shfl_xor(ps, 16); ps += __shfl_xor(ps, 32);
        const float inv = 1.0f / ps;

        const float* vrow = values + ((k * 64 + o) << 7) + q * 4;
        float* orow = out + ((((size_t)b * 8 + k) * 64 + o) << 7) + q * 4;
        #pragma unroll
        for (int mt = 0; mt < 8; ++mt) {
            floatx4 vv = *(const floatx4*)(vrow + mt * 16);
            floatx4 g;
            g[0] = zz[4 * mt + 0] * inv * vv[0];
            g[1] = zz[4 * mt + 1] * inv * vv[1];
            g[2] = zz[4 * mt + 2] * inv * vv[2];
            g[3] = zz[4 * mt + 3] * inv * vv[3];
            *(floatx4*)(orow + mt * 16) = g;
        }

        #pragma unroll
        for (int kk = 0; kk < 4; ++kk) bcur[kk] = bnxt[kk];
    }
}

extern "C" void kernel_launch(void* const* d_in, const int* in_sizes, int n_in,
                              void* d_out, int out_size, void* d_ws, size_t ws_size,
                              hipStream_t stream) {
    const float* xg     = (const float*)d_in[0];   // [2048,128,128]
    const float* bw     = (const float*)d_in[1];   // [8,128,64]
    const float* qm     = (const float*)d_in[2];   // [8,64,64]
    const float* values = (const float*)d_in[3];   // [8,64,128]
    float* out = (float*)d_out;                    // [2048,8,64,128]
    _Float16* W2h = (_Float16*)d_ws;               // 65536 halves = 128 KB

    w2_kernel<<<64, 256, 0, stream>>>(bw, qm, W2h);
    satt_kernel<<<2048, 256, 0, stream>>>(xg, W2h, values, out);
}

// Round 6
// 826.918 us; speedup vs baseline: 1.1195x; 1.1195x over previous
//
#include <hip/hip_runtime.h>
#include <hip/hip_bf16.h>

// out[b,k,o,f] = entmax15( x[b,f,:] @ W2'[k,:,o] ) * values[k,o,f]
// W2'[k,x,o] = 0.0625 * sum_y bw[k,x,y] * q[k,o,y]   (scale * (alpha-1) folded in)
// b=2048, k=8, o=64, f=128, x=128, y=64
//
// Round-6: round-5 structure (block = one b, x[b] staged fp16 LDS once,
// k-loop 0..7 with 32 ds_read+MFMA, in-register entmax) with the SPILL fixed:
// round-5 had VGPR=64 + ~1GB scratch traffic (zz[32] copy alongside acc +
// unroll-2 k-loop blew the 4-wave register cap). Fixes: no zz copy (fp32
// passes read acc[mt][r] directly), #pragma unroll 1 on k-loop, no B-frag
// software prefetch (W2h is L2-resident; TLP at 16 waves/CU hides it),
// nontemporal output stores.

using half8_t  = __attribute__((ext_vector_type(8))) _Float16;
using half4_t  = __attribute__((ext_vector_type(4))) _Float16;
using fp16x2   = __attribute__((ext_vector_type(2))) __fp16;   // builtin-compatible
using floatx4  = __attribute__((ext_vector_type(4))) float;

#define NBIS 8    // fp16 bisection iters -> bracket width 0.91*2^-8*2 = 7.1e-3

#if defined(__has_builtin)
#if __has_builtin(__builtin_amdgcn_fdot2)
#define HAS_FDOT2 1
#endif
#endif
#ifndef HAS_FDOT2
#define HAS_FDOT2 0
#endif

__device__ __forceinline__ float frcp(float x) {
#if __has_builtin(__builtin_amdgcn_rcpf)
    return __builtin_amdgcn_rcpf(x);   // 1-ulp rcp; plenty for Newton step sizing
#else
    return 1.0f / x;
#endif
}

// ---------------- Kernel A: W2'[k][o][x] fp16 into workspace ----------------
__global__ __launch_bounds__(256) void w2_kernel(const float* __restrict__ bw,
                                                 const float* __restrict__ qm,
                                                 _Float16* __restrict__ W2h) {
    const int k  = blockIdx.x >> 3;
    const int og = blockIdx.x & 7;          // o-chunk of 8 rows
    __shared__ float Lbw[128 * 65];         // [x][y] padded (+1) -> conflict-free
    __shared__ float Lq[8 * 64];            // [o][y]
    const int t = threadIdx.x;

    const float* bwk = bw + k * 8192;       // [128][64]
    #pragma unroll
    for (int i2 = 0; i2 < 8; ++i2) {
        int i = t + i2 * 256;               // float4 index, 2048 total
        float4 v = ((const float4*)bwk)[i];
        int xx = (i * 4) >> 6, y = (i * 4) & 63;
        float* dst = &Lbw[xx * 65 + y];
        dst[0] = v.x; dst[1] = v.y; dst[2] = v.z; dst[3] = v.w;
    }
    const float* qk = qm + k * 4096 + og * 8 * 64;
    if (t < 128) ((float4*)Lq)[t] = ((const float4*)qk)[t];
    __syncthreads();

    #pragma unroll
    for (int i = 0; i < 4; ++i) {
        int ox = i * 256 + t;               // 1024 outputs: [8 o][128 x]
        int o = ox >> 7, x = ox & 127;
        const float* brow = &Lbw[x * 65];
        const float* qrow = &Lq[o * 64];
        float acc = 0.f;
        #pragma unroll
        for (int y = 0; y < 64; ++y) acc = fmaf(brow[y], qrow[y], acc);
        W2h[(k * 64 + og * 8 + o) * 128 + x] = (_Float16)(acc * 0.0625f);
    }
}

// ---------------- Kernel B: fused GEMM + entmax + scale ----------------
// block = one b; 4 waves; wave qtr owns o in [16*qtr, 16*qtr+16); k-loop 0..7
__global__ __launch_bounds__(256, 4) void satt_kernel(
        const float* __restrict__ xg, const _Float16* __restrict__ W2h,
        const float* __restrict__ values, float* __restrict__ out) {
    const int b = blockIdx.x;
    const int t = threadIdx.x;
    const int qtr = t >> 6, l = t & 63;
    const int q = l >> 4, c16 = l & 15;
    const int o = qtr * 16 + c16;           // this lane's output row (all k)

    __shared__ _Float16 Ash[128 * 136];     // x[b] [f][x] fp16, padded row 136

    // ---- stage x[b] fp32 -> fp16 LDS once (4096 float4, 16/thread) ----
    const float* xb = xg + (size_t)b * 16384;
    #pragma unroll
    for (int j = 0; j < 16; ++j) {
        int c = t + 256 * j;
        int f = c >> 5, x0 = (c & 31) * 4;
        float4 v = ((const float4*)xb)[c];
        half4_t h;
        h[0] = (_Float16)v.x; h[1] = (_Float16)v.y;
        h[2] = (_Float16)v.z; h[3] = (_Float16)v.w;
        *(half4_t*)(&Ash[f * 136 + x0]) = h;
    }
    __syncthreads();

    const _Float16* w2o = W2h + (o << 7) + q * 8;   // + k*8192 per k

    #pragma unroll 1
    for (int k = 0; k < 8; ++k) {
        // B-frags for this k (W2h is 128 KB -> L2-resident; TLP hides latency)
        half8_t bcur[4];
        const _Float16* w2k = w2o + (k << 13);
        #pragma unroll
        for (int kk = 0; kk < 4; ++kk)
            bcur[kk] = *(const half8_t*)(w2k + kk * 32);

        // ---- MFMA: z^T[f,o]; A row = f = mt*16+c16 from LDS, B = W2 row o ----
        floatx4 acc[8];
        #pragma unroll
        for (int mt = 0; mt < 8; ++mt) acc[mt] = (floatx4){0.f, 0.f, 0.f, 0.f};
        #pragma unroll
        for (int kk = 0; kk < 4; ++kk) {
            #pragma unroll
            for (int mt = 0; mt < 8; ++mt) {
                half8_t a = *(const half8_t*)(&Ash[(mt * 16 + c16) * 136 + kk * 32 + q * 8]);
                acc[mt] = __builtin_amdgcn_mfma_f32_16x16x32_f16(a, bcur[kk], acc[mt], 0, 0, 0);
            }
        }

        // ---- Entmax-1.5; lane holds f = mt*16 + q*4 + r of row o ----
        // partners (same c16, q 0..3) are lanes l^16, l^32.
        // NOTE: fp32 z lives ONLY in acc[mt][r] (no copy -> no spill).
        float m0 = acc[0][0], m1 = acc[0][1], m2 = acc[0][2], m3 = acc[0][3];
        #pragma unroll
        for (int mt = 1; mt < 8; ++mt) {
            m0 = fmaxf(m0, acc[mt][0]); m1 = fmaxf(m1, acc[mt][1]);
            m2 = fmaxf(m2, acc[mt][2]); m3 = fmaxf(m3, acc[mt][3]);
        }
        float m = fmaxf(fmaxf(m0, m1), fmaxf(m2, m3));
        m = fmaxf(m, __shfl_xor(m, 16));
        m = fmaxf(m, __shfl_xor(m, 32));

        float tau = m - 1.0f;
        float dm  = 0.9116116523516816f;    // 1 - (1/128)^0.5

#if HAS_FDOT2
        fp16x2 zh[16];
        #pragma unroll
        for (int mt = 0; mt < 8; ++mt) {
            zh[2 * mt + 0] = __builtin_amdgcn_cvt_pkrtz(acc[mt][0], acc[mt][1]);
            zh[2 * mt + 1] = __builtin_amdgcn_cvt_pkrtz(acc[mt][2], acc[mt][3]);
        }
        const fp16x2 hzero = { (__fp16)0.f, (__fp16)0.f };
        const fp16x2 hone  = { (__fp16)1.f, (__fp16)1.f };

        #pragma unroll
        for (int it = 0; it < NBIS; ++it) {
            dm *= 0.5f;
            float tm = tau + dm;
            fp16x2 t2 = __builtin_amdgcn_cvt_pkrtz(tm, tm);
            float sa = 0.f, sb = 0.f;
            #pragma unroll
            for (int j = 0; j < 16; j += 2) {
                fp16x2 d0 = __builtin_elementwise_max(zh[j]     - t2, hzero);
                fp16x2 d1 = __builtin_elementwise_max(zh[j + 1] - t2, hzero);
                sa = __builtin_amdgcn_fdot2(d0, d0, sa, false);
                sb = __builtin_amdgcn_fdot2(d1, d1, sb, false);
            }
            float sm = sa + sb;
            sm += __shfl_xor(sm, 16); sm += __shfl_xor(sm, 32);
            tau = (sm >= 1.0f) ? tm : tau;  // f(m-1) >= 0 -> sign test vs 1
        }
        // 2 fp16 Newton steps (monotone for convex f)
        #pragma unroll
        for (int it = 0; it < 2; ++it) {
            fp16x2 t2 = __builtin_amdgcn_cvt_pkrtz(tau, tau);
            float s2a = 0.f, s2b = 0.f, s1a = 0.f, s1b = 0.f;
            #pragma unroll
            for (int j = 0; j < 16; j += 2) {
                fp16x2 d0 = __builtin_elementwise_max(zh[j]     - t2, hzero);
                fp16x2 d1 = __builtin_elementwise_max(zh[j + 1] - t2, hzero);
                s2a = __builtin_amdgcn_fdot2(d0, d0, s2a, false);
                s2b = __builtin_amdgcn_fdot2(d1, d1, s2b, false);
                s1a = __builtin_amdgcn_fdot2(d0, hone, s1a, false);
                s1b = __builtin_amdgcn_fdot2(d1, hone, s1b, false);
            }
            float s2 = s2a + s2b, s1 = s1a + s1b;
            s2 += __shfl_xor(s2, 16); s2 += __shfl_xor(s2, 32);
            s1 += __shfl_xor(s1, 16); s1 += __shfl_xor(s1, 32);
            tau += (s2 - 1.0f) * frcp(fmaxf(s1 + s1, 1e-6f));
        }
#else
        #pragma unroll
        for (int it = 0; it < NBIS + 4; ++it) {
            dm *= 0.5f;
            float tm = tau + dm;
            float sa = 0.f, sb = 0.f;
            #pragma unroll
            for (int mt = 0; mt < 8; ++mt) {
                float d0 = fmaxf(acc[mt][0] - tm, 0.f);
                float d1 = fmaxf(acc[mt][1] - tm, 0.f);
                float d2 = fmaxf(acc[mt][2] - tm, 0.f);
                float d3 = fmaxf(acc[mt][3] - tm, 0.f);
                sa = fmaf(d0, d0, sa); sb = fmaf(d1, d1, sb);
                sa = fmaf(d2, d2, sa); sb = fmaf(d3, d3, sb);
            }
            float sm = sa + sb;
            sm += __shfl_xor(sm, 16); sm += __shfl_xor(sm, 32);
            tau = (sm >= 1.0f) ? tm : tau;
        }
        {
            float s2 = 0.f, s1 = 0.f;
            #pragma unroll
            for (int mt = 0; mt < 8; ++mt) {
                #pragma unroll
                for (int r = 0; r < 4; ++r) {
                    float d = fmaxf(acc[mt][r] - tau, 0.f);
                    s2 = fmaf(d, d, s2); s1 += d;
                }
            }
            s2 += __shfl_xor(s2, 16); s2 += __shfl_xor(s2, 32);
            s1 += __shfl_xor(s1, 16); s1 += __shfl_xor(s1, 32);
            tau += (s2 - 1.0f) * frcp(fmaxf(s1 + s1, 1e-6f));
        }
#endif
        // final fp32 Newton polish (removes fp16 root bias; err -> ~1e-5)
        {
            float s2a = 0.f, s2b = 0.f, s1a = 0.f, s1b = 0.f;
            #pragma unroll
            for (int mt = 0; mt < 8; ++mt) {
                float d0 = fmaxf(acc[mt][0] - tau, 0.f);
                float d1 = fmaxf(acc[mt][1] - tau, 0.f);
                float d2 = fmaxf(acc[mt][2] - tau, 0.f);
                float d3 = fmaxf(acc[mt][3] - tau, 0.f);
                s2a = fmaf(d0, d0, s2a); s2b = fmaf(d1, d1, s2b);
                s2a = fmaf(d2, d2, s2a); s2b = fmaf(d3, d3, s2b);
                s1a += d0 + d2; s1b += d1 + d3;
            }
            float s2 = s2a + s2b, s1 = s1a + s1b;
            s2 += __shfl_xor(s2, 16); s2 += __shfl_xor(s2, 32);
            s1 += __shfl_xor(s1, 16); s1 += __shfl_xor(s1, 32);
            tau += (s2 - 1.0f) * frcp(fmaxf(s1 + s1, 1e-6f));
        }

        // final p (overwrite acc in place), normalize, scale by values, store
        float ps0 = 0.f, ps1 = 0.f;
        #pragma unroll
        for (int mt = 0; mt < 8; ++mt) {
            float d0 = fmaxf(acc[mt][0] - tau, 0.f);
            float d1 = fmaxf(acc[mt][1] - tau, 0.f);
            float d2 = fmaxf(acc[mt][2] - tau, 0.f);
            float d3 = fmaxf(acc[mt][3] - tau, 0.f);
            float p0 = d0 * d0, p1 = d1 * d1, p2 = d2 * d2, p3 = d3 * d3;
            acc[mt][0] = p0; acc[mt][1] = p1; acc[mt][2] = p2; acc[mt][3] = p3;
            ps0 += p0 + p2; ps1 += p1 + p3;
        }
        float ps = ps0 + ps1;
        ps += __shfl_xor(ps, 16); ps += __shfl_xor(ps, 32);
        const float inv = 1.0f / ps;

        const float* vrow = values + ((k * 64 + o) << 7) + q * 4;
        float* orow = out + ((((size_t)b * 8 + k) * 64 + o) << 7) + q * 4;
        #pragma unroll
        for (int mt = 0; mt < 8; ++mt) {
            floatx4 vv = *(const floatx4*)(vrow + mt * 16);
            floatx4 g;
            g[0] = acc[mt][0] * inv * vv[0];
            g[1] = acc[mt][1] * inv * vv[1];
            g[2] = acc[mt][2] * inv * vv[2];
            g[3] = acc[mt][3] * inv * vv[3];
            __builtin_nontemporal_store(g, (floatx4*)(orow + mt * 16));
        }
    }
}

extern "C" void kernel_launch(void* const* d_in, const int* in_sizes, int n_in,
                              void* d_out, int out_size, void* d_ws, size_t ws_size,
                              hipStream_t stream) {
    const float* xg     = (const float*)d_in[0];   // [2048,128,128]
    const float* bw     = (const float*)d_in[1];   // [8,128,64]
    const float* qm     = (const float*)d_in[2];   // [8,64,64]
    const float* values = (const float*)d_in[3];   // [8,64,128]
    float* out = (float*)d_out;                    // [2048,8,64,128]
    _Float16* W2h = (_Float16*)d_ws;               // 65536 halves = 128 KB

    w2_kernel<<<64, 256, 0, stream>>>(bw, qm, W2h);
    satt_kernel<<<2048, 256, 0, stream>>>(xg, W2h, values, out);
}